// Round 8
// baseline (118.099 us; speedup 1.0000x reference)
//
#include <hip/hip_runtime.h>
#include <math.h>

#define NB  4
#define NLQ 256
#define NLK 512
#define NH  256

// scale folded into projections: exp2(SC*(q+k)) = exp(2*(q+k))
#define SCALE_2LOG2E 2.885390081777927f
#define LOG2E        1.4426950408889634f

// ---------------------------------------------------------------------------
// Setup: W transposes (blocks 0..31) + per-batch mask compaction (32..35).
// ---------------------------------------------------------------------------
__global__ __launch_bounds__(256) void setup_kernel(
    const float* __restrict__ Wq, const float* __restrict__ Wk,
    const int* __restrict__ mask,
    float* __restrict__ Wtq, float* __restrict__ Wtk,
    int* __restrict__ act, int* __restrict__ nact)
{
    const int blk = blockIdx.x;
    const int t   = threadIdx.x;

    if (blk < 32) {
        // ---- transpose one 64x64 tile of Wq/Wk into Wtq/Wtk ----
        __shared__ float ts[64][65];
        const int m    = blk >> 4;               // 0: Wq, 1: Wk
        const int tile = blk & 15;
        const int h0 = (tile >> 2) * 64;
        const int c0 = (tile & 3) * 64;
        const float* W  = m ? Wk  : Wq;
        float*       Wt = m ? Wtk : Wtq;
        const int lr = t >> 4, lc = t & 15;
        #pragma unroll
        for (int i = 0; i < 4; ++i) {
            const int r = lr + 16 * i;
            const float4 d = *(const float4*)(W + (size_t)(h0 + r) * NH + c0 + lc * 4);
            ts[r][lc * 4 + 0] = d.x;
            ts[r][lc * 4 + 1] = d.y;
            ts[r][lc * 4 + 2] = d.z;
            ts[r][lc * 4 + 3] = d.w;
        }
        __syncthreads();
        #pragma unroll
        for (int i = 0; i < 4; ++i) {
            const int c = lr + 16 * i;
            float4 d;
            d.x = ts[lc * 4 + 0][c];
            d.y = ts[lc * 4 + 1][c];
            d.z = ts[lc * 4 + 2][c];
            d.w = ts[lc * 4 + 3][c];
            *(float4*)(Wt + (size_t)(c0 + c) * NH + h0 + lc * 4) = d;
        }
    } else if (blk < 32 + NB) {
        // ---- mask compaction for batch b ----
        const int b = blk - 32;
        __shared__ int wcnt[8], wpre[9];
        const int lane = t & 63, wave = t >> 6;
        const int k1 = t, k2 = t + 256;
        const int m1 = mask[b * NLK + k1];
        const int m2 = mask[b * NLK + k2];
        const unsigned long long below = (1ULL << lane) - 1ULL;
        const unsigned long long bal1 = __ballot(m1 != 0);
        const unsigned long long bal2 = __ballot(m2 != 0);
        const int r1 = __popcll(bal1 & below);
        const int r2 = __popcll(bal2 & below);
        if (lane == 0) { wcnt[wave] = __popcll(bal1); wcnt[4 + wave] = __popcll(bal2); }
        __syncthreads();
        if (t == 0) {
            int s = 0;
            #pragma unroll
            for (int w = 0; w < 8; ++w) { wpre[w] = s; s += wcnt[w]; }
            wpre[8] = s;
        }
        __syncthreads();
        const int na = wpre[8];
        if (m1) act[b * NLK + wpre[wave]     + r1] = k1;
        if (m2) act[b * NLK + wpre[4 + wave] + r2] = k2;
        if (k1 >= na) act[b * NLK + k1] = 0;     // safe tail for padded reads
        if (k2 >= na) act[b * NLK + k2] = 0;
        if (t == 0) nact[b] = na;
    }
}

// ---------------------------------------------------------------------------
// Fused projections, 16 rows/block (4x the arithmetic intensity on W^T:
// 196 -> 49 MB of weight refetch, the dominant prep cost).
// Blocks 0..63: q rows (16/block) -> qp = exp2(scaled proj).
// Blocks 64..191: compact k slots (16/block via act) -> kp_ct transposed.
// XCD batch affinity: b = idx&3 (both sections are multiples of 8 blocks).
// Combine in 4 row-groups through a reused 16 KB LDS buffer; per-output
// reduction tree identical to the 4-row version (bit-identical results).
// ---------------------------------------------------------------------------
__global__ __launch_bounds__(256) void prep_kernel(
    const float* __restrict__ query, const float* __restrict__ key,
    const float* __restrict__ Wtq, const float* __restrict__ bq,
    const float* __restrict__ Wtk, const float* __restrict__ bk,
    const int* __restrict__ act, const int* __restrict__ nact,
    float* __restrict__ qp, float* __restrict__ kp_ct)
{
    const int blk  = blockIdx.x;
    const int t    = threadIdx.x;
    const int wave = t >> 6;
    const int lane = t & 63;

    __shared__ float  xs[16][NH];        // 16 KB inputs
    __shared__ float4 ps[4][4][64];      // 16 KB partials (one 4-row group)
    __shared__ int    ridx[16];

    const float *Wt, *bias;
    int b = 0, j0 = 0, r0 = 0, na = 0;
    const bool isq = (blk < 64);

    if (isq) {
        b  = blk & 3;                            // XCD affinity
        r0 = b * NLQ + (blk >> 2) * 16;          // global q-row
        #pragma unroll
        for (int i = 0; i < 4; ++i) {
            const int idx4 = t + 256 * i;        // 0..1023
            const int row = idx4 >> 6, c4 = idx4 & 63;
            ((float4*)&xs[0][0])[idx4] =
                ((const float4*)(query + (size_t)(r0 + row) * NH))[c4];
        }
        Wt = Wtq; bias = bq;
    } else {
        const int idx = blk - 64;
        b  = idx & 3;                            // XCD affinity
        j0 = (idx >> 2) * 16;
        na = nact[b];
        if (j0 >= na) return;
        if (t < 16) ridx[t] = act[b * NLK + ((j0 + t < na) ? (j0 + t) : j0)];
        __syncthreads();
        #pragma unroll
        for (int i = 0; i < 4; ++i) {
            const int idx4 = t + 256 * i;
            const int row = idx4 >> 6, c4 = idx4 & 63;
            ((float4*)&xs[0][0])[idx4] =
                ((const float4*)(key + ((size_t)b * NLK + ridx[row]) * NH))[c4];
        }
        Wt = Wtk; bias = bk;
    }
    __syncthreads();

    float4 acc[16];
    #pragma unroll
    for (int r = 0; r < 16; ++r) acc[r] = (float4){0.f, 0.f, 0.f, 0.f};

    const int cbase = wave * 64;
    #pragma unroll 2
    for (int cc = 0; cc < 64; ++cc) {
        const int c = cbase + cc;
        const float4 w = *(const float4*)(Wt + (size_t)c * NH + lane * 4);
        #pragma unroll
        for (int r = 0; r < 16; ++r) {
            const float xv = xs[r][c];             // LDS broadcast
            acc[r].x = fmaf(xv, w.x, acc[r].x);
            acc[r].y = fmaf(xv, w.y, acc[r].y);
            acc[r].z = fmaf(xv, w.z, acc[r].z);
            acc[r].w = fmaf(xv, w.w, acc[r].w);
        }
    }

    // combine + store, 4 rows per group (reuse ps buffer)
    for (int g = 0; g < 4; ++g) {
        __syncthreads();                           // prior group's reads done
        #pragma unroll
        for (int r = 0; r < 4; ++r) ps[wave][r][lane] = acc[g * 4 + r];
        __syncthreads();

        // thread t -> group-row r = wave, h-quad l = lane
        const int r = wave, l = lane;
        const float4 p0 = ps[0][r][l], p1 = ps[1][r][l];
        const float4 p2 = ps[2][r][l], p3 = ps[3][r][l];
        const float4 bb = *(const float4*)(bias + l * 4);
        float4 o;
        o.x = (p0.x + p1.x + p2.x + p3.x + bb.x) * SCALE_2LOG2E;
        o.y = (p0.y + p1.y + p2.y + p3.y + bb.y) * SCALE_2LOG2E;
        o.z = (p0.z + p1.z + p2.z + p3.z + bb.z) * SCALE_2LOG2E;
        o.w = (p0.w + p1.w + p2.w + p3.w + bb.w) * SCALE_2LOG2E;
        o.x = __builtin_amdgcn_exp2f(o.x);
        o.y = __builtin_amdgcn_exp2f(o.y);
        o.z = __builtin_amdgcn_exp2f(o.z);
        o.w = __builtin_amdgcn_exp2f(o.w);

        const int rg = g * 4 + r;                  // row within block (0..15)
        if (isq) {
            *(float4*)(qp + (size_t)(r0 + rg) * NH + l * 4) = o;
        } else if (j0 + rg < na) {
            const int j = j0 + rg;
            kp_ct[((size_t)b * NH + l * 4 + 0) * NLK + j] = o.x;
            kp_ct[((size_t)b * NH + l * 4 + 1) * NLK + j] = o.y;
            kp_ct[((size_t)b * NH + l * 4 + 2) * NLK + j] = o.z;
            kp_ct[((size_t)b * NH + l * 4 + 3) * NLK + j] = o.w;
        }
    }
}

// ---------------------------------------------------------------------------
// Fused attn — EXACT R4 structure (best measured: 106.8 us total).
// Block = 512 threads (8 waves), 2 q rows, grid = 512.
// XCD batch affinity: b = blk&3. Single score pass: wave = h-octant (32 c);
// lane owns slots 4l..4l+3 and (na>256, block-uniform) 256+4l..256+4l+3.
// Partials [2][8][512] = 32 KB; combine stride-1. Softmax: waves 0/1.
// Output: j ≡ wave mod 8; one float4 value load feeds 2 rows; 8-way reduce.
// ---------------------------------------------------------------------------
__global__ __launch_bounds__(512) void attn_kernel(
    const float* __restrict__ qp, const float* __restrict__ kp_ct,
    const float* __restrict__ value, const int* __restrict__ mask,
    const int* __restrict__ act, const int* __restrict__ nact,
    const float* __restrict__ vvec,
    float* __restrict__ out_o, float* __restrict__ out_w)
{
    __shared__ float sc0[NLK], sc1[NLK];
    __shared__ int   actl[NLK];
    __shared__ float eqs[2][NH];
    __shared__ float vvs[NH];
    __shared__ float4 buf4[2048];  // 32 KB: score partials [2][8][512] / out partials [2][512]

    const int blk  = blockIdx.x;
    const int b    = blk & 3;                // XCD batch affinity
    const int q0   = (blk >> 2) * 2;         // 128 q-pairs per batch
    const int t    = threadIdx.x;            // 0..511
    const int lane = t & 63;
    const int wave = t >> 6;                 // 0..7

    const int na = nact[b];
    actl[t] = (t < na) ? act[b * NLK + t] : 0;
    if (t < NH) {
        eqs[0][t] = qp[(size_t)(b * NLQ + q0) * NH + t];
        eqs[1][t] = qp[(size_t)(b * NLQ + q0 + 1) * NH + t];
        vvs[t]    = vvec[t];
    }

    // zero masked out_w slots for this block's 2 rows (scatter fills actives)
    float* w0row = out_w + (size_t)(b * NLQ + q0) * NLK;
    float* w1row = w0row + NLK;
    if (!mask[b * NLK + t]) { w0row[t] = 0.f; w1row[t] = 0.f; }
    __syncthreads();                         // eqs/vvs/actl ready

    const int cb = wave * 32;                // h-octant for this wave
    const float* kb  = kp_ct + ((size_t)b * NH + cb) * NLK;
    const float* eq0 = &eqs[0][cb];
    const float* eq1 = &eqs[1][cb];
    const float* vv  = &vvs[cb];

    // ---- single score pass ----
    float4 a0 = {0.f, 0.f, 0.f, 0.f}, a1 = {0.f, 0.f, 0.f, 0.f};  // slots 4l..
    float4 a2 = {0.f, 0.f, 0.f, 0.f}, a3 = {0.f, 0.f, 0.f, 0.f};  // slots 256+4l..
    if (na > 256) {
        #pragma unroll 4
        for (int c = 0; c < 32; ++c) {
            const float4 k1 = *(const float4*)(kb + (size_t)c * NLK + 4 * lane);
            const float4 k2 = *(const float4*)(kb + (size_t)c * NLK + 256 + 4 * lane);
            const float eqa = eq0[c];        // wave-uniform LDS broadcast
            const float eqb = eq1[c];
            const float vh  = vv[c];
            a0.x = fmaf(vh, __builtin_amdgcn_rcpf(fmaf(eqa, k1.x, 1.f)), a0.x);
            a0.y = fmaf(vh, __builtin_amdgcn_rcpf(fmaf(eqa, k1.y, 1.f)), a0.y);
            a0.z = fmaf(vh, __builtin_amdgcn_rcpf(fmaf(eqa, k1.z, 1.f)), a0.z);
            a0.w = fmaf(vh, __builtin_amdgcn_rcpf(fmaf(eqa, k1.w, 1.f)), a0.w);
            a1.x = fmaf(vh, __builtin_amdgcn_rcpf(fmaf(eqb, k1.x, 1.f)), a1.x);
            a1.y = fmaf(vh, __builtin_amdgcn_rcpf(fmaf(eqb, k1.y, 1.f)), a1.y);
            a1.z = fmaf(vh, __builtin_amdgcn_rcpf(fmaf(eqb, k1.z, 1.f)), a1.z);
            a1.w = fmaf(vh, __builtin_amdgcn_rcpf(fmaf(eqb, k1.w, 1.f)), a1.w);
            a2.x = fmaf(vh, __builtin_amdgcn_rcpf(fmaf(eqa, k2.x, 1.f)), a2.x);
            a2.y = fmaf(vh, __builtin_amdgcn_rcpf(fmaf(eqa, k2.y, 1.f)), a2.y);
            a2.z = fmaf(vh, __builtin_amdgcn_rcpf(fmaf(eqa, k2.z, 1.f)), a2.z);
            a2.w = fmaf(vh, __builtin_amdgcn_rcpf(fmaf(eqa, k2.w, 1.f)), a2.w);
            a3.x = fmaf(vh, __builtin_amdgcn_rcpf(fmaf(eqb, k2.x, 1.f)), a3.x);
            a3.y = fmaf(vh, __builtin_amdgcn_rcpf(fmaf(eqb, k2.y, 1.f)), a3.y);
            a3.z = fmaf(vh, __builtin_amdgcn_rcpf(fmaf(eqb, k2.z, 1.f)), a3.z);
            a3.w = fmaf(vh, __builtin_amdgcn_rcpf(fmaf(eqb, k2.w, 1.f)), a3.w);
        }
    } else {
        #pragma unroll 4
        for (int c = 0; c < 32; ++c) {
            const float4 k1 = *(const float4*)(kb + (size_t)c * NLK + 4 * lane);
            const float eqa = eq0[c];
            const float eqb = eq1[c];
            const float vh  = vv[c];
            a0.x = fmaf(vh, __builtin_amdgcn_rcpf(fmaf(eqa, k1.x, 1.f)), a0.x);
            a0.y = fmaf(vh, __builtin_amdgcn_rcpf(fmaf(eqa, k1.y, 1.f)), a0.y);
            a0.z = fmaf(vh, __builtin_amdgcn_rcpf(fmaf(eqa, k1.z, 1.f)), a0.z);
            a0.w = fmaf(vh, __builtin_amdgcn_rcpf(fmaf(eqa, k1.w, 1.f)), a0.w);
            a1.x = fmaf(vh, __builtin_amdgcn_rcpf(fmaf(eqb, k1.x, 1.f)), a1.x);
            a1.y = fmaf(vh, __builtin_amdgcn_rcpf(fmaf(eqb, k1.y, 1.f)), a1.y);
            a1.z = fmaf(vh, __builtin_amdgcn_rcpf(fmaf(eqb, k1.z, 1.f)), a1.z);
            a1.w = fmaf(vh, __builtin_amdgcn_rcpf(fmaf(eqb, k1.w, 1.f)), a1.w);
        }
    }
    // partials as float[2][8][512]: buf4[(r*8+w)*128 + half*64 + lane]
    buf4[(0 * 8 + wave) * 128 + lane]      = a0;
    buf4[(0 * 8 + wave) * 128 + 64 + lane] = a2;
    buf4[(1 * 8 + wave) * 128 + lane]      = a1;
    buf4[(1 * 8 + wave) * 128 + 64 + lane] = a3;
    __syncthreads();
    {
        // combine: thread t -> slot t for both rows; 8 octant adds each
        const float* pf = (const float*)buf4;
        float sA = 0.f, sB = 0.f;
        #pragma unroll
        for (int o = 0; o < 8; ++o) {
            sA += pf[o * 512 + t];           // conflict-free stride-1
            sB += pf[(8 + o) * 512 + t];
        }
        sc0[t] = (t < na) ? -2.f * sA : -INFINITY;
        sc1[t] = (t < na) ? -2.f * sB : -INFINITY;
    }
    __syncthreads();

    // ---- softmax: wave 0 -> q row 0, wave 1 -> q row 1 (512 slots) ----
    if (wave < 2) {
        float* row = wave ? sc1 : sc0;
        float vals[8];
        float m = -INFINITY;
        #pragma unroll
        for (int j8 = 0; j8 < 8; ++j8) {
            vals[j8] = row[lane + j8 * 64];
            m = fmaxf(m, vals[j8]);
        }
        #pragma unroll
        for (int s = 32; s >= 1; s >>= 1)
            m = fmaxf(m, __shfl_xor(m, s, 64));
        float sum = 0.0f;
        #pragma unroll
        for (int j8 = 0; j8 < 8; ++j8) {
            vals[j8] = __builtin_amdgcn_exp2f((vals[j8] - m) * LOG2E);
            sum += vals[j8];
        }
        #pragma unroll
        for (int s = 32; s >= 1; s >>= 1)
            sum += __shfl_xor(sum, s, 64);
        const float inv = __builtin_amdgcn_rcpf(sum);
        float* wout = out_w + (size_t)(b * NLQ + q0 + wave) * NLK;
        #pragma unroll
        for (int j8 = 0; j8 < 8; ++j8) {
            const int jj = lane + j8 * 64;
            const float w = vals[j8] * inv;
            row[jj] = w;                      // 0 for jj >= na
            if (jj < na) wout[actl[jj]] = w;  // masked slots stay 0
        }
    }
    __syncthreads();

    // ---- output: j split across 8 waves (j ≡ wave mod 8), thread owns
    //      4 columns via one float4 value load; 8-way LDS reduce after ----
    {
        const int c4 = lane * 4;
        const float* vb = value + (size_t)b * NLK * NH + c4;
        float4 o0 = {0.f, 0.f, 0.f, 0.f}, o1 = {0.f, 0.f, 0.f, 0.f};
        #pragma unroll 4
        for (int j = wave; j < na; j += 8) {
            const float w0 = sc0[j];          // wave-uniform LDS broadcast
            const float w1 = sc1[j];
            const int   rj = actl[j];
            const float4 v4 = *(const float4*)(vb + (size_t)rj * NH);
            o0.x = fmaf(w0, v4.x, o0.x); o0.y = fmaf(w0, v4.y, o0.y);
            o0.z = fmaf(w0, v4.z, o0.z); o0.w = fmaf(w0, v4.w, o0.w);
            o1.x = fmaf(w1, v4.x, o1.x); o1.y = fmaf(w1, v4.y, o1.y);
            o1.z = fmaf(w1, v4.z, o1.z); o1.w = fmaf(w1, v4.w, o1.w);
        }
        buf4[t]       = o0;                   // row 0 partials
        buf4[512 + t] = o1;                   // row 1 partials
        __syncthreads();
        if (t < 128) {
            const int row = t >> 6;           // 0 or 1
            const int l   = t & 63;
            float4 o = buf4[row * 512 + l];
            #pragma unroll
            for (int w = 1; w < 8; ++w) {
                const float4 s = buf4[row * 512 + l + 64 * w];
                o.x += s.x; o.y += s.y; o.z += s.z; o.w += s.w;
            }
            *(float4*)(out_o + (size_t)(b * NLQ + q0 + row) * NH + l * 4) = o;
        }
    }
}

// ---------------------------------------------------------------------------
extern "C" void kernel_launch(void* const* d_in, const int* in_sizes, int n_in,
                              void* d_out, int out_size, void* d_ws, size_t ws_size,
                              hipStream_t stream) {
    const float* query = (const float*)d_in[0];
    const float* key   = (const float*)d_in[1];
    const float* value = (const float*)d_in[2];
    const int*   mask  = (const int*)  d_in[3];
    const float* Wq    = (const float*)d_in[4];
    const float* bq    = (const float*)d_in[5];
    const float* Wk    = (const float*)d_in[6];
    const float* bk    = (const float*)d_in[7];
    const float* v     = (const float*)d_in[8];
    // d_in[9] (bv) drops out of softmax -> unused

    float* out_o = (float*)d_out;                     // [4,256,256]
    float* out_w = out_o + NB * NLQ * NH;             // [4,256,512]

    float* qp    = (float*)d_ws;                      // [4,256,256] Eq
    float* kp_ct = qp + NB * NLQ * NH;                // [4,256,512] Ek compact-T
    int*   act   = (int*)(kp_ct + NB * NH * NLK);     // [4,512]
    int*   nact  = act + NB * NLK;                    // [4]

    const size_t base = (size_t)(NB * NLQ * NH) + (size_t)(NB * NH * NLK)
                      + NB * NLK + NB;                // floats+ints consumed
    float* wtq;
    if (ws_size >= (base + 2 * NH * NH) * sizeof(float)) {
        wtq = (float*)d_ws + base;                    // workspace tail
    } else {
        // park W^T in the out_w tail; attn (after prep) overwrites out_w
        wtq = out_w + (size_t)NB * NLQ * NLK - 2 * NH * NH;
    }
    float* wtk = wtq + NH * NH;

    setup_kernel<<<36, 256, 0, stream>>>(Wq, Wk, mask, wtq, wtk, act, nact);
    prep_kernel<<<64 + 128, 256, 0, stream>>>(
        query, key, wtq, bq, wtk, bk, act, nact, qp, kp_ct);
    attn_kernel<<<NB * NLQ / 2, 512, 0, stream>>>(
        qp, kp_ct, value, mask, act, nact, v, out_o, out_w);
}

// Round 9
// 109.703 us; speedup vs baseline: 1.0765x; 1.0765x over previous
//
#include <hip/hip_runtime.h>
#include <math.h>

#define NB  4
#define NLQ 256
#define NLK 512
#define NH  256

// scale folded into projections: exp2(SC*(q+k)) = exp(2*(q+k))
#define SCALE_2LOG2E 2.885390081777927f
#define LOG2E        1.4426950408889634f

// ---------------------------------------------------------------------------
// Setup: W transposes (blocks 0..31) + per-batch mask compaction (32..35).
// ---------------------------------------------------------------------------
__global__ __launch_bounds__(256) void setup_kernel(
    const float* __restrict__ Wq, const float* __restrict__ Wk,
    const int* __restrict__ mask,
    float* __restrict__ Wtq, float* __restrict__ Wtk,
    int* __restrict__ act, int* __restrict__ nact)
{
    const int blk = blockIdx.x;
    const int t   = threadIdx.x;

    if (blk < 32) {
        // ---- transpose one 64x64 tile of Wq/Wk into Wtq/Wtk ----
        __shared__ float ts[64][65];
        const int m    = blk >> 4;               // 0: Wq, 1: Wk
        const int tile = blk & 15;
        const int h0 = (tile >> 2) * 64;
        const int c0 = (tile & 3) * 64;
        const float* W  = m ? Wk  : Wq;
        float*       Wt = m ? Wtk : Wtq;
        const int lr = t >> 4, lc = t & 15;
        #pragma unroll
        for (int i = 0; i < 4; ++i) {
            const int r = lr + 16 * i;
            const float4 d = *(const float4*)(W + (size_t)(h0 + r) * NH + c0 + lc * 4);
            ts[r][lc * 4 + 0] = d.x;
            ts[r][lc * 4 + 1] = d.y;
            ts[r][lc * 4 + 2] = d.z;
            ts[r][lc * 4 + 3] = d.w;
        }
        __syncthreads();
        #pragma unroll
        for (int i = 0; i < 4; ++i) {
            const int c = lr + 16 * i;
            float4 d;
            d.x = ts[lc * 4 + 0][c];
            d.y = ts[lc * 4 + 1][c];
            d.z = ts[lc * 4 + 2][c];
            d.w = ts[lc * 4 + 3][c];
            *(float4*)(Wt + (size_t)(c0 + c) * NH + h0 + lc * 4) = d;
        }
    } else if (blk < 32 + NB) {
        // ---- mask compaction for batch b ----
        const int b = blk - 32;
        __shared__ int wcnt[8], wpre[9];
        const int lane = t & 63, wave = t >> 6;
        const int k1 = t, k2 = t + 256;
        const int m1 = mask[b * NLK + k1];
        const int m2 = mask[b * NLK + k2];
        const unsigned long long below = (1ULL << lane) - 1ULL;
        const unsigned long long bal1 = __ballot(m1 != 0);
        const unsigned long long bal2 = __ballot(m2 != 0);
        const int r1 = __popcll(bal1 & below);
        const int r2 = __popcll(bal2 & below);
        if (lane == 0) { wcnt[wave] = __popcll(bal1); wcnt[4 + wave] = __popcll(bal2); }
        __syncthreads();
        if (t == 0) {
            int s = 0;
            #pragma unroll
            for (int w = 0; w < 8; ++w) { wpre[w] = s; s += wcnt[w]; }
            wpre[8] = s;
        }
        __syncthreads();
        const int na = wpre[8];
        if (m1) act[b * NLK + wpre[wave]     + r1] = k1;
        if (m2) act[b * NLK + wpre[4 + wave] + r2] = k2;
        if (k1 >= na) act[b * NLK + k1] = 0;     // safe tail for padded reads
        if (k2 >= na) act[b * NLK + k2] = 0;
        if (t == 0) nact[b] = na;
    }
}

// ---------------------------------------------------------------------------
// Fused projections (c-split across waves, coalesced Wt loads) — R4 version.
// XCD batch affinity: b = idx&3. 768 blocks (3/CU, 12 waves/CU).
// Blocks 0..255: q rows (4/block) -> qp = exp2(scaled proj).
// Blocks 256..767: compact k slots (4/block via act) -> kp_ct transposed.
// ---------------------------------------------------------------------------
__global__ __launch_bounds__(256) void prep_kernel(
    const float* __restrict__ query, const float* __restrict__ key,
    const float* __restrict__ Wtq, const float* __restrict__ bq,
    const float* __restrict__ Wtk, const float* __restrict__ bk,
    const int* __restrict__ act, const int* __restrict__ nact,
    float* __restrict__ qp, float* __restrict__ kp_ct)
{
    const int blk  = blockIdx.x;
    const int t    = threadIdx.x;
    const int wave = t >> 6;
    const int lane = t & 63;

    __shared__ float  xs[4][NH];
    __shared__ float4 ps[4][4][64];
    __shared__ int    ridx[4];

    const float *Wt, *bias;
    int b = 0, j0 = 0, r0 = 0, na = 0;
    const bool isq = (blk < NB * NLQ / 4);

    if (isq) {
        b  = blk & 3;                            // XCD affinity
        r0 = b * NLQ + (blk >> 2) * 4;           // global q-row
        ((float4*)&xs[0][0])[t] = ((const float4*)(query + (size_t)r0 * NH))[t];
        Wt = Wtq; bias = bq;
    } else {
        const int idx = blk - 256;
        b  = idx & 3;                            // XCD affinity
        j0 = (idx >> 2) * 4;
        na = nact[b];
        if (j0 >= na) return;
        if (t < 4) ridx[t] = act[b * NLK + ((j0 + t < na) ? (j0 + t) : j0)];
        __syncthreads();
        const int r = t >> 6, c4 = t & 63;
        ((float4*)xs[r])[c4] =
            ((const float4*)(key + ((size_t)b * NLK + ridx[r]) * NH))[c4];
        Wt = Wtk; bias = bk;
    }
    __syncthreads();

    float4 acc[4];
    #pragma unroll
    for (int r = 0; r < 4; ++r) acc[r] = (float4){0.f, 0.f, 0.f, 0.f};

    const int cbase = wave * 64;
    #pragma unroll 4
    for (int cc = 0; cc < 64; ++cc) {
        const int c = cbase + cc;
        const float4 w = *(const float4*)(Wt + (size_t)c * NH + lane * 4);
        #pragma unroll
        for (int r = 0; r < 4; ++r) {
            const float xv = xs[r][c];             // LDS broadcast
            acc[r].x = fmaf(xv, w.x, acc[r].x);
            acc[r].y = fmaf(xv, w.y, acc[r].y);
            acc[r].z = fmaf(xv, w.z, acc[r].z);
            acc[r].w = fmaf(xv, w.w, acc[r].w);
        }
    }
    #pragma unroll
    for (int r = 0; r < 4; ++r) ps[wave][r][lane] = acc[r];
    __syncthreads();

    // combine: thread t -> row r = wave, h-quad l = lane
    const int r = wave, l = lane;
    const float4 p0 = ps[0][r][l], p1 = ps[1][r][l];
    const float4 p2 = ps[2][r][l], p3 = ps[3][r][l];
    const float4 bb = *(const float4*)(bias + l * 4);
    float4 o;
    o.x = (p0.x + p1.x + p2.x + p3.x + bb.x) * SCALE_2LOG2E;
    o.y = (p0.y + p1.y + p2.y + p3.y + bb.y) * SCALE_2LOG2E;
    o.z = (p0.z + p1.z + p2.z + p3.z + bb.z) * SCALE_2LOG2E;
    o.w = (p0.w + p1.w + p2.w + p3.w + bb.w) * SCALE_2LOG2E;
    // E-values: exp2 hoisted out of the attn inner loop
    o.x = __builtin_amdgcn_exp2f(o.x);
    o.y = __builtin_amdgcn_exp2f(o.y);
    o.z = __builtin_amdgcn_exp2f(o.z);
    o.w = __builtin_amdgcn_exp2f(o.w);

    if (isq) {
        *(float4*)(qp + (size_t)(r0 + r) * NH + l * 4) = o;
    } else if (j0 + r < na) {
        const int j = j0 + r;
        kp_ct[((size_t)b * NH + l * 4 + 0) * NLK + j] = o.x;
        kp_ct[((size_t)b * NH + l * 4 + 1) * NLK + j] = o.y;
        kp_ct[((size_t)b * NH + l * 4 + 2) * NLK + j] = o.z;
        kp_ct[((size_t)b * NH + l * 4 + 3) * NLK + j] = o.w;
    }
}

// ---------------------------------------------------------------------------
// Fused attn — R4 structure (best measured) + capacity-matched overflow.
// Block = 512 threads (8 waves), 2 q rows, grid = 512. b = blk&3 affinity.
// Score: wave = h-octant (32 c); lane owns slots 4l..4l+3 (float4 Ek load).
// Overflow slots (na>256):
//   * 256 < na <= 320 (typical: na ~ 256±12): lane additionally owns ONE
//     slot 256+lane via a scalar coalesced load -> 10 rcp/c vs 16 (-37%).
//   * na > 320 (safety fallback): full second float4 half, as in R4.
// Per-slot reduction tree identical in all paths (within-wave c-accum +
// 8-way octant sum) -> bit-identical results. Unwritten partial regions are
// only read for slots >= na, which the combine masks to -INF.
// Softmax: waves 0/1. Output: j ≡ wave mod 8; float4 value loads; 8-way
// LDS reduce (reusing the partial buffer).
// ---------------------------------------------------------------------------
__global__ __launch_bounds__(512) void attn_kernel(
    const float* __restrict__ qp, const float* __restrict__ kp_ct,
    const float* __restrict__ value, const int* __restrict__ mask,
    const int* __restrict__ act, const int* __restrict__ nact,
    const float* __restrict__ vvec,
    float* __restrict__ out_o, float* __restrict__ out_w)
{
    __shared__ float sc0[NLK], sc1[NLK];
    __shared__ int   actl[NLK];
    __shared__ float eqs[2][NH];
    __shared__ float vvs[NH];
    __shared__ float4 buf4[2048];  // 32 KB: score partials [2][8][512]f / out partials [2][512]f4

    const int blk  = blockIdx.x;
    const int b    = blk & 3;                // XCD batch affinity
    const int q0   = (blk >> 2) * 2;         // 128 q-pairs per batch
    const int t    = threadIdx.x;            // 0..511
    const int lane = t & 63;
    const int wave = t >> 6;                 // 0..7

    const int na = nact[b];
    actl[t] = (t < na) ? act[b * NLK + t] : 0;
    if (t < NH) {
        eqs[0][t] = qp[(size_t)(b * NLQ + q0) * NH + t];
        eqs[1][t] = qp[(size_t)(b * NLQ + q0 + 1) * NH + t];
        vvs[t]    = vvec[t];
    }

    // zero masked out_w slots for this block's 2 rows (scatter fills actives)
    float* w0row = out_w + (size_t)(b * NLQ + q0) * NLK;
    float* w1row = w0row + NLK;
    if (!mask[b * NLK + t]) { w0row[t] = 0.f; w1row[t] = 0.f; }
    __syncthreads();                         // eqs/vvs/actl ready

    const int cb = wave * 32;                // h-octant for this wave
    const float* kb  = kp_ct + ((size_t)b * NH + cb) * NLK;
    const float* eq0 = &eqs[0][cb];
    const float* eq1 = &eqs[1][cb];
    const float* vv  = &vvs[cb];

    // ---- single score pass (3 block-uniform variants) ----
    float4 a0 = {0.f, 0.f, 0.f, 0.f}, a1 = {0.f, 0.f, 0.f, 0.f};  // slots 4l..
    if (na > 256 && na <= 320) {
        // typical overflow: one extra slot per lane (256+lane)
        float ov0 = 0.f, ov1 = 0.f;
        #pragma unroll 4
        for (int c = 0; c < 32; ++c) {
            const float4 k1 = *(const float4*)(kb + (size_t)c * NLK + 4 * lane);
            const float  ko = kb[(size_t)c * NLK + 256 + lane];
            const float eqa = eq0[c];        // wave-uniform LDS broadcast
            const float eqb = eq1[c];
            const float vh  = vv[c];
            a0.x = fmaf(vh, __builtin_amdgcn_rcpf(fmaf(eqa, k1.x, 1.f)), a0.x);
            a0.y = fmaf(vh, __builtin_amdgcn_rcpf(fmaf(eqa, k1.y, 1.f)), a0.y);
            a0.z = fmaf(vh, __builtin_amdgcn_rcpf(fmaf(eqa, k1.z, 1.f)), a0.z);
            a0.w = fmaf(vh, __builtin_amdgcn_rcpf(fmaf(eqa, k1.w, 1.f)), a0.w);
            a1.x = fmaf(vh, __builtin_amdgcn_rcpf(fmaf(eqb, k1.x, 1.f)), a1.x);
            a1.y = fmaf(vh, __builtin_amdgcn_rcpf(fmaf(eqb, k1.y, 1.f)), a1.y);
            a1.z = fmaf(vh, __builtin_amdgcn_rcpf(fmaf(eqb, k1.z, 1.f)), a1.z);
            a1.w = fmaf(vh, __builtin_amdgcn_rcpf(fmaf(eqb, k1.w, 1.f)), a1.w);
            ov0  = fmaf(vh, __builtin_amdgcn_rcpf(fmaf(eqa, ko, 1.f)), ov0);
            ov1  = fmaf(vh, __builtin_amdgcn_rcpf(fmaf(eqb, ko, 1.f)), ov1);
        }
        buf4[(0 * 8 + wave) * 128 + lane] = a0;
        buf4[(1 * 8 + wave) * 128 + lane] = a1;
        ((float*)buf4)[(0 * 8 + wave) * 512 + 256 + lane] = ov0;
        ((float*)buf4)[(1 * 8 + wave) * 512 + 256 + lane] = ov1;
    } else if (na > 320) {
        // safety fallback: full second half (slots 256+4l..), as in R4
        float4 a2 = {0.f, 0.f, 0.f, 0.f}, a3 = {0.f, 0.f, 0.f, 0.f};
        #pragma unroll 4
        for (int c = 0; c < 32; ++c) {
            const float4 k1 = *(const float4*)(kb + (size_t)c * NLK + 4 * lane);
            const float4 k2 = *(const float4*)(kb + (size_t)c * NLK + 256 + 4 * lane);
            const float eqa = eq0[c];
            const float eqb = eq1[c];
            const float vh  = vv[c];
            a0.x = fmaf(vh, __builtin_amdgcn_rcpf(fmaf(eqa, k1.x, 1.f)), a0.x);
            a0.y = fmaf(vh, __builtin_amdgcn_rcpf(fmaf(eqa, k1.y, 1.f)), a0.y);
            a0.z = fmaf(vh, __builtin_amdgcn_rcpf(fmaf(eqa, k1.z, 1.f)), a0.z);
            a0.w = fmaf(vh, __builtin_amdgcn_rcpf(fmaf(eqa, k1.w, 1.f)), a0.w);
            a1.x = fmaf(vh, __builtin_amdgcn_rcpf(fmaf(eqb, k1.x, 1.f)), a1.x);
            a1.y = fmaf(vh, __builtin_amdgcn_rcpf(fmaf(eqb, k1.y, 1.f)), a1.y);
            a1.z = fmaf(vh, __builtin_amdgcn_rcpf(fmaf(eqb, k1.z, 1.f)), a1.z);
            a1.w = fmaf(vh, __builtin_amdgcn_rcpf(fmaf(eqb, k1.w, 1.f)), a1.w);
            a2.x = fmaf(vh, __builtin_amdgcn_rcpf(fmaf(eqa, k2.x, 1.f)), a2.x);
            a2.y = fmaf(vh, __builtin_amdgcn_rcpf(fmaf(eqa, k2.y, 1.f)), a2.y);
            a2.z = fmaf(vh, __builtin_amdgcn_rcpf(fmaf(eqa, k2.z, 1.f)), a2.z);
            a2.w = fmaf(vh, __builtin_amdgcn_rcpf(fmaf(eqa, k2.w, 1.f)), a2.w);
            a3.x = fmaf(vh, __builtin_amdgcn_rcpf(fmaf(eqb, k2.x, 1.f)), a3.x);
            a3.y = fmaf(vh, __builtin_amdgcn_rcpf(fmaf(eqb, k2.y, 1.f)), a3.y);
            a3.z = fmaf(vh, __builtin_amdgcn_rcpf(fmaf(eqb, k2.z, 1.f)), a3.z);
            a3.w = fmaf(vh, __builtin_amdgcn_rcpf(fmaf(eqb, k2.w, 1.f)), a3.w);
        }
        buf4[(0 * 8 + wave) * 128 + lane]      = a0;
        buf4[(0 * 8 + wave) * 128 + 64 + lane] = a2;
        buf4[(1 * 8 + wave) * 128 + lane]      = a1;
        buf4[(1 * 8 + wave) * 128 + 64 + lane] = a3;
    } else {
        // na <= 256: main half only
        #pragma unroll 4
        for (int c = 0; c < 32; ++c) {
            const float4 k1 = *(const float4*)(kb + (size_t)c * NLK + 4 * lane);
            const float eqa = eq0[c];
            const float eqb = eq1[c];
            const float vh  = vv[c];
            a0.x = fmaf(vh, __builtin_amdgcn_rcpf(fmaf(eqa, k1.x, 1.f)), a0.x);
            a0.y = fmaf(vh, __builtin_amdgcn_rcpf(fmaf(eqa, k1.y, 1.f)), a0.y);
            a0.z = fmaf(vh, __builtin_amdgcn_rcpf(fmaf(eqa, k1.z, 1.f)), a0.z);
            a0.w = fmaf(vh, __builtin_amdgcn_rcpf(fmaf(eqa, k1.w, 1.f)), a0.w);
            a1.x = fmaf(vh, __builtin_amdgcn_rcpf(fmaf(eqb, k1.x, 1.f)), a1.x);
            a1.y = fmaf(vh, __builtin_amdgcn_rcpf(fmaf(eqb, k1.y, 1.f)), a1.y);
            a1.z = fmaf(vh, __builtin_amdgcn_rcpf(fmaf(eqb, k1.z, 1.f)), a1.z);
            a1.w = fmaf(vh, __builtin_amdgcn_rcpf(fmaf(eqb, k1.w, 1.f)), a1.w);
        }
        buf4[(0 * 8 + wave) * 128 + lane] = a0;
        buf4[(1 * 8 + wave) * 128 + lane] = a1;
    }
    __syncthreads();
    {
        // combine: thread t -> slot t for both rows; 8 octant adds each.
        // Slots >= na read unwritten/garbage partials but are masked below.
        const float* pf = (const float*)buf4;
        float sA = 0.f, sB = 0.f;
        #pragma unroll
        for (int o = 0; o < 8; ++o) {
            sA += pf[o * 512 + t];           // conflict-free stride-1
            sB += pf[(8 + o) * 512 + t];
        }
        sc0[t] = (t < na) ? -2.f * sA : -INFINITY;
        sc1[t] = (t < na) ? -2.f * sB : -INFINITY;
    }
    __syncthreads();

    // ---- softmax: wave 0 -> q row 0, wave 1 -> q row 1 (512 slots) ----
    if (wave < 2) {
        float* row = wave ? sc1 : sc0;
        float vals[8];
        float m = -INFINITY;
        #pragma unroll
        for (int j8 = 0; j8 < 8; ++j8) {
            vals[j8] = row[lane + j8 * 64];
            m = fmaxf(m, vals[j8]);
        }
        #pragma unroll
        for (int s = 32; s >= 1; s >>= 1)
            m = fmaxf(m, __shfl_xor(m, s, 64));
        float sum = 0.0f;
        #pragma unroll
        for (int j8 = 0; j8 < 8; ++j8) {
            vals[j8] = __builtin_amdgcn_exp2f((vals[j8] - m) * LOG2E);
            sum += vals[j8];
        }
        #pragma unroll
        for (int s = 32; s >= 1; s >>= 1)
            sum += __shfl_xor(sum, s, 64);
        const float inv = __builtin_amdgcn_rcpf(sum);
        float* wout = out_w + (size_t)(b * NLQ + q0 + wave) * NLK;
        #pragma unroll
        for (int j8 = 0; j8 < 8; ++j8) {
            const int jj = lane + j8 * 64;
            const float w = vals[j8] * inv;
            row[jj] = w;                      // 0 for jj >= na
            if (jj < na) wout[actl[jj]] = w;  // masked slots stay 0
        }
    }
    __syncthreads();

    // ---- output: j split across 8 waves (j ≡ wave mod 8), thread owns
    //      4 columns via one float4 value load; 8-way LDS reduce after ----
    {
        const int c4 = lane * 4;
        const float* vb = value + (size_t)b * NLK * NH + c4;
        float4 o0 = {0.f, 0.f, 0.f, 0.f}, o1 = {0.f, 0.f, 0.f, 0.f};
        #pragma unroll 4
        for (int j = wave; j < na; j += 8) {
            const float w0 = sc0[j];          // wave-uniform LDS broadcast
            const float w1 = sc1[j];
            const int   rj = actl[j];
            const float4 v4 = *(const float4*)(vb + (size_t)rj * NH);
            o0.x = fmaf(w0, v4.x, o0.x); o0.y = fmaf(w0, v4.y, o0.y);
            o0.z = fmaf(w0, v4.z, o0.z); o0.w = fmaf(w0, v4.w, o0.w);
            o1.x = fmaf(w1, v4.x, o1.x); o1.y = fmaf(w1, v4.y, o1.y);
            o1.z = fmaf(w1, v4.z, o1.z); o1.w = fmaf(w1, v4.w, o1.w);
        }
        __syncthreads();                     // combine reads done; reuse buf4
        buf4[t]       = o0;                   // row 0 partials
        buf4[512 + t] = o1;                   // row 1 partials
        __syncthreads();
        if (t < 128) {
            const int row = t >> 6;           // 0 or 1
            const int l   = t & 63;
            float4 o = buf4[row * 512 + l];
            #pragma unroll
            for (int w = 1; w < 8; ++w) {
                const float4 s = buf4[row * 512 + l + 64 * w];
                o.x += s.x; o.y += s.y; o.z += s.z; o.w += s.w;
            }
            *(float4*)(out_o + (size_t)(b * NLQ + q0 + row) * NH + l * 4) = o;
        }
    }
}

// ---------------------------------------------------------------------------
extern "C" void kernel_launch(void* const* d_in, const int* in_sizes, int n_in,
                              void* d_out, int out_size, void* d_ws, size_t ws_size,
                              hipStream_t stream) {
    const float* query = (const float*)d_in[0];
    const float* key   = (const float*)d_in[1];
    const float* value = (const float*)d_in[2];
    const int*   mask  = (const int*)  d_in[3];
    const float* Wq    = (const float*)d_in[4];
    const float* bq    = (const float*)d_in[5];
    const float* Wk    = (const float*)d_in[6];
    const float* bk    = (const float*)d_in[7];
    const float* v     = (const float*)d_in[8];
    // d_in[9] (bv) drops out of softmax -> unused

    float* out_o = (float*)d_out;                     // [4,256,256]
    float* out_w = out_o + NB * NLQ * NH;             // [4,256,512]

    float* qp    = (float*)d_ws;                      // [4,256,256] Eq
    float* kp_ct = qp + NB * NLQ * NH;                // [4,256,512] Ek compact-T
    int*   act   = (int*)(kp_ct + NB * NH * NLK);     // [4,512]
    int*   nact  = act + NB * NLK;                    // [4]

    const size_t base = (size_t)(NB * NLQ * NH) + (size_t)(NB * NH * NLK)
                      + NB * NLK + NB;                // floats+ints consumed
    float* wtq;
    if (ws_size >= (base + 2 * NH * NH) * sizeof(float)) {
        wtq = (float*)d_ws + base;                    // workspace tail
    } else {
        // park W^T in the out_w tail; attn (after prep) overwrites out_w
        wtq = out_w + (size_t)NB * NLQ * NLK - 2 * NH * NH;
    }
    float* wtk = wtq + NH * NH;

    setup_kernel<<<36, 256, 0, stream>>>(Wq, Wk, mask, wtq, wtk, act, nact);
    prep_kernel<<<NB * NLQ / 4 + NB * NLK / 4, 256, 0, stream>>>(
        query, key, wtq, bq, wtk, bk, act, nact, qp, kp_ct);
    attn_kernel<<<NB * NLQ / 2, 512, 0, stream>>>(
        qp, kp_ct, value, mask, act, nact, v, out_o, out_w);
}

// Round 10
// 107.493 us; speedup vs baseline: 1.0987x; 1.0206x over previous
//
#include <hip/hip_runtime.h>
#include <math.h>

#define NB  4
#define NLQ 256
#define NLK 512
#define NH  256

// scale folded into projections: exp2(SC*(q+k)) = exp(2*(q+k))
#define SCALE_2LOG2E 2.885390081777927f
#define LOG2E        1.4426950408889634f

// ---------------------------------------------------------------------------
// Setup: W transposes (blocks 0..31) + per-batch mask compaction (32..35).
// ---------------------------------------------------------------------------
__global__ __launch_bounds__(256) void setup_kernel(
    const float* __restrict__ Wq, const float* __restrict__ Wk,
    const int* __restrict__ mask,
    float* __restrict__ Wtq, float* __restrict__ Wtk,
    int* __restrict__ act, int* __restrict__ nact)
{
    const int blk = blockIdx.x;
    const int t   = threadIdx.x;

    if (blk < 32) {
        // ---- transpose one 64x64 tile of Wq/Wk into Wtq/Wtk ----
        __shared__ float ts[64][65];
        const int m    = blk >> 4;               // 0: Wq, 1: Wk
        const int tile = blk & 15;
        const int h0 = (tile >> 2) * 64;
        const int c0 = (tile & 3) * 64;
        const float* W  = m ? Wk  : Wq;
        float*       Wt = m ? Wtk : Wtq;
        const int lr = t >> 4, lc = t & 15;
        #pragma unroll
        for (int i = 0; i < 4; ++i) {
            const int r = lr + 16 * i;
            const float4 d = *(const float4*)(W + (size_t)(h0 + r) * NH + c0 + lc * 4);
            ts[r][lc * 4 + 0] = d.x;
            ts[r][lc * 4 + 1] = d.y;
            ts[r][lc * 4 + 2] = d.z;
            ts[r][lc * 4 + 3] = d.w;
        }
        __syncthreads();
        #pragma unroll
        for (int i = 0; i < 4; ++i) {
            const int c = lr + 16 * i;
            float4 d;
            d.x = ts[lc * 4 + 0][c];
            d.y = ts[lc * 4 + 1][c];
            d.z = ts[lc * 4 + 2][c];
            d.w = ts[lc * 4 + 3][c];
            *(float4*)(Wt + (size_t)(c0 + c) * NH + h0 + lc * 4) = d;
        }
    } else if (blk < 32 + NB) {
        // ---- mask compaction for batch b ----
        const int b = blk - 32;
        __shared__ int wcnt[8], wpre[9];
        const int lane = t & 63, wave = t >> 6;
        const int k1 = t, k2 = t + 256;
        const int m1 = mask[b * NLK + k1];
        const int m2 = mask[b * NLK + k2];
        const unsigned long long below = (1ULL << lane) - 1ULL;
        const unsigned long long bal1 = __ballot(m1 != 0);
        const unsigned long long bal2 = __ballot(m2 != 0);
        const int r1 = __popcll(bal1 & below);
        const int r2 = __popcll(bal2 & below);
        if (lane == 0) { wcnt[wave] = __popcll(bal1); wcnt[4 + wave] = __popcll(bal2); }
        __syncthreads();
        if (t == 0) {
            int s = 0;
            #pragma unroll
            for (int w = 0; w < 8; ++w) { wpre[w] = s; s += wcnt[w]; }
            wpre[8] = s;
        }
        __syncthreads();
        const int na = wpre[8];
        if (m1) act[b * NLK + wpre[wave]     + r1] = k1;
        if (m2) act[b * NLK + wpre[4 + wave] + r2] = k2;
        if (k1 >= na) act[b * NLK + k1] = 0;     // safe tail for padded reads
        if (k2 >= na) act[b * NLK + k2] = 0;
        if (t == 0) nact[b] = na;
    }
}

// ---------------------------------------------------------------------------
// Fused projections (c-split across waves, coalesced Wt loads) — R4 version.
// XCD batch affinity: b = idx&3. 768 blocks (3/CU, 12 waves/CU).
// Blocks 0..255: q rows (4/block) -> qp = exp2(scaled proj).
// Blocks 256..767: compact k slots (4/block via act) -> kp_ct transposed.
// ---------------------------------------------------------------------------
__global__ __launch_bounds__(256) void prep_kernel(
    const float* __restrict__ query, const float* __restrict__ key,
    const float* __restrict__ Wtq, const float* __restrict__ bq,
    const float* __restrict__ Wtk, const float* __restrict__ bk,
    const int* __restrict__ act, const int* __restrict__ nact,
    float* __restrict__ qp, float* __restrict__ kp_ct)
{
    const int blk  = blockIdx.x;
    const int t    = threadIdx.x;
    const int wave = t >> 6;
    const int lane = t & 63;

    __shared__ float  xs[4][NH];
    __shared__ float4 ps[4][4][64];
    __shared__ int    ridx[4];

    const float *Wt, *bias;
    int b = 0, j0 = 0, r0 = 0, na = 0;
    const bool isq = (blk < NB * NLQ / 4);

    if (isq) {
        b  = blk & 3;                            // XCD affinity
        r0 = b * NLQ + (blk >> 2) * 4;           // global q-row
        ((float4*)&xs[0][0])[t] = ((const float4*)(query + (size_t)r0 * NH))[t];
        Wt = Wtq; bias = bq;
    } else {
        const int idx = blk - 256;
        b  = idx & 3;                            // XCD affinity
        j0 = (idx >> 2) * 4;
        na = nact[b];
        if (j0 >= na) return;
        if (t < 4) ridx[t] = act[b * NLK + ((j0 + t < na) ? (j0 + t) : j0)];
        __syncthreads();
        const int r = t >> 6, c4 = t & 63;
        ((float4*)xs[r])[c4] =
            ((const float4*)(key + ((size_t)b * NLK + ridx[r]) * NH))[c4];
        Wt = Wtk; bias = bk;
    }
    __syncthreads();

    float4 acc[4];
    #pragma unroll
    for (int r = 0; r < 4; ++r) acc[r] = (float4){0.f, 0.f, 0.f, 0.f};

    const int cbase = wave * 64;
    #pragma unroll 4
    for (int cc = 0; cc < 64; ++cc) {
        const int c = cbase + cc;
        const float4 w = *(const float4*)(Wt + (size_t)c * NH + lane * 4);
        #pragma unroll
        for (int r = 0; r < 4; ++r) {
            const float xv = xs[r][c];             // LDS broadcast
            acc[r].x = fmaf(xv, w.x, acc[r].x);
            acc[r].y = fmaf(xv, w.y, acc[r].y);
            acc[r].z = fmaf(xv, w.z, acc[r].z);
            acc[r].w = fmaf(xv, w.w, acc[r].w);
        }
    }
    #pragma unroll
    for (int r = 0; r < 4; ++r) ps[wave][r][lane] = acc[r];
    __syncthreads();

    // combine: thread t -> row r = wave, h-quad l = lane
    const int r = wave, l = lane;
    const float4 p0 = ps[0][r][l], p1 = ps[1][r][l];
    const float4 p2 = ps[2][r][l], p3 = ps[3][r][l];
    const float4 bb = *(const float4*)(bias + l * 4);
    float4 o;
    o.x = (p0.x + p1.x + p2.x + p3.x + bb.x) * SCALE_2LOG2E;
    o.y = (p0.y + p1.y + p2.y + p3.y + bb.y) * SCALE_2LOG2E;
    o.z = (p0.z + p1.z + p2.z + p3.z + bb.z) * SCALE_2LOG2E;
    o.w = (p0.w + p1.w + p2.w + p3.w + bb.w) * SCALE_2LOG2E;
    // E-values: exp2 hoisted out of the attn inner loop
    o.x = __builtin_amdgcn_exp2f(o.x);
    o.y = __builtin_amdgcn_exp2f(o.y);
    o.z = __builtin_amdgcn_exp2f(o.z);
    o.w = __builtin_amdgcn_exp2f(o.w);

    if (isq) {
        *(float4*)(qp + (size_t)(r0 + r) * NH + l * 4) = o;
    } else if (j0 + r < na) {
        const int j = j0 + r;
        kp_ct[((size_t)b * NH + l * 4 + 0) * NLK + j] = o.x;
        kp_ct[((size_t)b * NH + l * 4 + 1) * NLK + j] = o.y;
        kp_ct[((size_t)b * NH + l * 4 + 2) * NLK + j] = o.z;
        kp_ct[((size_t)b * NH + l * 4 + 3) * NLK + j] = o.w;
    }
}

// ---------------------------------------------------------------------------
// Fused attn — R4 structure + paired-reciprocal score (exact rational merge).
// v0/a + v1/b = (v0*b + v1*a)*rcp(a*b): pairs along h (c, c+1) feeding the
// SAME slot accumulator -> rcp count HALVES (trans pipe is the score floor);
// garbage slots stay confined per-component (pairing never crosses slots).
// a,b <= ~2^30 -> a*b <= 2^60, no overflow.
// Block = 512 threads (8 waves), 2 q rows, grid = 512. b = blk&3 affinity.
// Overflow slots (na>256): one extra scalar slot/lane for na<=320, full
// second float4 half fallback for na>320. Combine/softmax/output as R4.
// ---------------------------------------------------------------------------
#define PR(acc_, eA_, kA_, eB_, kB_, vA_, vB_) {                               \
    const float da_ = fmaf(eA_, kA_, 1.f);                                     \
    const float db_ = fmaf(eB_, kB_, 1.f);                                     \
    const float nm_ = fmaf(vB_, da_, vA_ * db_);                               \
    acc_ = fmaf(nm_, __builtin_amdgcn_rcpf(da_ * db_), acc_); }

__global__ __launch_bounds__(512) void attn_kernel(
    const float* __restrict__ qp, const float* __restrict__ kp_ct,
    const float* __restrict__ value, const int* __restrict__ mask,
    const int* __restrict__ act, const int* __restrict__ nact,
    const float* __restrict__ vvec,
    float* __restrict__ out_o, float* __restrict__ out_w)
{
    __shared__ float sc0[NLK], sc1[NLK];
    __shared__ int   actl[NLK];
    __shared__ float eqs[2][NH];
    __shared__ float vvs[NH];
    __shared__ float4 buf4[2048];  // 32 KB: score partials [2][8][512]f / out partials [2][512]f4

    const int blk  = blockIdx.x;
    const int b    = blk & 3;                // XCD batch affinity
    const int q0   = (blk >> 2) * 2;         // 128 q-pairs per batch
    const int t    = threadIdx.x;            // 0..511
    const int lane = t & 63;
    const int wave = t >> 6;                 // 0..7

    const int na = nact[b];
    actl[t] = (t < na) ? act[b * NLK + t] : 0;
    if (t < NH) {
        eqs[0][t] = qp[(size_t)(b * NLQ + q0) * NH + t];
        eqs[1][t] = qp[(size_t)(b * NLQ + q0 + 1) * NH + t];
        vvs[t]    = vvec[t];
    }

    // zero masked out_w slots for this block's 2 rows (scatter fills actives)
    float* w0row = out_w + (size_t)(b * NLQ + q0) * NLK;
    float* w1row = w0row + NLK;
    if (!mask[b * NLK + t]) { w0row[t] = 0.f; w1row[t] = 0.f; }
    __syncthreads();                         // eqs/vvs/actl ready

    const int cb = wave * 32;                // h-octant for this wave
    const float* kb  = kp_ct + ((size_t)b * NH + cb) * NLK;
    const float* eq0 = &eqs[0][cb];
    const float* eq1 = &eqs[1][cb];
    const float* vv  = &vvs[cb];

    // ---- single score pass (3 block-uniform variants, c-paired rcp) ----
    float4 a0 = {0.f, 0.f, 0.f, 0.f}, a1 = {0.f, 0.f, 0.f, 0.f};  // slots 4l..
    if (na > 256 && na <= 320) {
        // typical overflow: one extra slot per lane (256+lane)
        float ov0 = 0.f, ov1 = 0.f;
        #pragma unroll 4
        for (int c = 0; c < 32; c += 2) {
            const float4 kA = *(const float4*)(kb + (size_t)c * NLK + 4 * lane);
            const float4 kB = *(const float4*)(kb + (size_t)(c + 1) * NLK + 4 * lane);
            const float koA = kb[(size_t)c * NLK + 256 + lane];
            const float koB = kb[(size_t)(c + 1) * NLK + 256 + lane];
            const float e0A = eq0[c], e0B = eq0[c + 1];   // wave-uniform LDS
            const float e1A = eq1[c], e1B = eq1[c + 1];
            const float vA  = vv[c],  vB  = vv[c + 1];
            PR(a0.x, e0A, kA.x, e0B, kB.x, vA, vB)
            PR(a0.y, e0A, kA.y, e0B, kB.y, vA, vB)
            PR(a0.z, e0A, kA.z, e0B, kB.z, vA, vB)
            PR(a0.w, e0A, kA.w, e0B, kB.w, vA, vB)
            PR(a1.x, e1A, kA.x, e1B, kB.x, vA, vB)
            PR(a1.y, e1A, kA.y, e1B, kB.y, vA, vB)
            PR(a1.z, e1A, kA.z, e1B, kB.z, vA, vB)
            PR(a1.w, e1A, kA.w, e1B, kB.w, vA, vB)
            PR(ov0,  e0A, koA,  e0B, koB,  vA, vB)
            PR(ov1,  e1A, koA,  e1B, koB,  vA, vB)
        }
        buf4[(0 * 8 + wave) * 128 + lane] = a0;
        buf4[(1 * 8 + wave) * 128 + lane] = a1;
        ((float*)buf4)[(0 * 8 + wave) * 512 + 256 + lane] = ov0;
        ((float*)buf4)[(1 * 8 + wave) * 512 + 256 + lane] = ov1;
    } else if (na > 320) {
        // safety fallback: full second half (slots 256+4l..)
        float4 a2 = {0.f, 0.f, 0.f, 0.f}, a3 = {0.f, 0.f, 0.f, 0.f};
        #pragma unroll 2
        for (int c = 0; c < 32; c += 2) {
            const float4 kA  = *(const float4*)(kb + (size_t)c * NLK + 4 * lane);
            const float4 kB  = *(const float4*)(kb + (size_t)(c + 1) * NLK + 4 * lane);
            const float4 k2A = *(const float4*)(kb + (size_t)c * NLK + 256 + 4 * lane);
            const float4 k2B = *(const float4*)(kb + (size_t)(c + 1) * NLK + 256 + 4 * lane);
            const float e0A = eq0[c], e0B = eq0[c + 1];
            const float e1A = eq1[c], e1B = eq1[c + 1];
            const float vA  = vv[c],  vB  = vv[c + 1];
            PR(a0.x, e0A, kA.x,  e0B, kB.x,  vA, vB)
            PR(a0.y, e0A, kA.y,  e0B, kB.y,  vA, vB)
            PR(a0.z, e0A, kA.z,  e0B, kB.z,  vA, vB)
            PR(a0.w, e0A, kA.w,  e0B, kB.w,  vA, vB)
            PR(a1.x, e1A, kA.x,  e1B, kB.x,  vA, vB)
            PR(a1.y, e1A, kA.y,  e1B, kB.y,  vA, vB)
            PR(a1.z, e1A, kA.z,  e1B, kB.z,  vA, vB)
            PR(a1.w, e1A, kA.w,  e1B, kB.w,  vA, vB)
            PR(a2.x, e0A, k2A.x, e0B, k2B.x, vA, vB)
            PR(a2.y, e0A, k2A.y, e0B, k2B.y, vA, vB)
            PR(a2.z, e0A, k2A.z, e0B, k2B.z, vA, vB)
            PR(a2.w, e0A, k2A.w, e0B, k2B.w, vA, vB)
            PR(a3.x, e1A, k2A.x, e1B, k2B.x, vA, vB)
            PR(a3.y, e1A, k2A.y, e1B, k2B.y, vA, vB)
            PR(a3.z, e1A, k2A.z, e1B, k2B.z, vA, vB)
            PR(a3.w, e1A, k2A.w, e1B, k2B.w, vA, vB)
        }
        buf4[(0 * 8 + wave) * 128 + lane]      = a0;
        buf4[(0 * 8 + wave) * 128 + 64 + lane] = a2;
        buf4[(1 * 8 + wave) * 128 + lane]      = a1;
        buf4[(1 * 8 + wave) * 128 + 64 + lane] = a3;
    } else {
        // na <= 256: main half only
        #pragma unroll 4
        for (int c = 0; c < 32; c += 2) {
            const float4 kA = *(const float4*)(kb + (size_t)c * NLK + 4 * lane);
            const float4 kB = *(const float4*)(kb + (size_t)(c + 1) * NLK + 4 * lane);
            const float e0A = eq0[c], e0B = eq0[c + 1];
            const float e1A = eq1[c], e1B = eq1[c + 1];
            const float vA  = vv[c],  vB  = vv[c + 1];
            PR(a0.x, e0A, kA.x, e0B, kB.x, vA, vB)
            PR(a0.y, e0A, kA.y, e0B, kB.y, vA, vB)
            PR(a0.z, e0A, kA.z, e0B, kB.z, vA, vB)
            PR(a0.w, e0A, kA.w, e0B, kB.w, vA, vB)
            PR(a1.x, e1A, kA.x, e1B, kB.x, vA, vB)
            PR(a1.y, e1A, kA.y, e1B, kB.y, vA, vB)
            PR(a1.z, e1A, kA.z, e1B, kB.z, vA, vB)
            PR(a1.w, e1A, kA.w, e1B, kB.w, vA, vB)
        }
        buf4[(0 * 8 + wave) * 128 + lane] = a0;
        buf4[(1 * 8 + wave) * 128 + lane] = a1;
    }
    __syncthreads();
    {
        // combine: thread t -> slot t for both rows; 8 octant adds each.
        // Slots >= na read unwritten/garbage partials but are masked below.
        const float* pf = (const float*)buf4;
        float sA = 0.f, sB = 0.f;
        #pragma unroll
        for (int o = 0; o < 8; ++o) {
            sA += pf[o * 512 + t];           // conflict-free stride-1
            sB += pf[(8 + o) * 512 + t];
        }
        sc0[t] = (t < na) ? -2.f * sA : -INFINITY;
        sc1[t] = (t < na) ? -2.f * sB : -INFINITY;
    }
    __syncthreads();

    // ---- softmax: wave 0 -> q row 0, wave 1 -> q row 1 (512 slots) ----
    if (wave < 2) {
        float* row = wave ? sc1 : sc0;
        float vals[8];
        float m = -INFINITY;
        #pragma unroll
        for (int j8 = 0; j8 < 8; ++j8) {
            vals[j8] = row[lane + j8 * 64];
            m = fmaxf(m, vals[j8]);
        }
        #pragma unroll
        for (int s = 32; s >= 1; s >>= 1)
            m = fmaxf(m, __shfl_xor(m, s, 64));
        float sum = 0.0f;
        #pragma unroll
        for (int j8 = 0; j8 < 8; ++j8) {
            vals[j8] = __builtin_amdgcn_exp2f((vals[j8] - m) * LOG2E);
            sum += vals[j8];
        }
        #pragma unroll
        for (int s = 32; s >= 1; s >>= 1)
            sum += __shfl_xor(sum, s, 64);
        const float inv = __builtin_amdgcn_rcpf(sum);
        float* wout = out_w + (size_t)(b * NLQ + q0 + wave) * NLK;
        #pragma unroll
        for (int j8 = 0; j8 < 8; ++j8) {
            const int jj = lane + j8 * 64;
            const float w = vals[j8] * inv;
            row[jj] = w;                      // 0 for jj >= na
            if (jj < na) wout[actl[jj]] = w;  // masked slots stay 0
        }
    }
    __syncthreads();

    // ---- output: j split across 8 waves (j ≡ wave mod 8), thread owns
    //      4 columns via one float4 value load; 8-way LDS reduce after ----
    {
        const int c4 = lane * 4;
        const float* vb = value + (size_t)b * NLK * NH + c4;
        float4 o0 = {0.f, 0.f, 0.f, 0.f}, o1 = {0.f, 0.f, 0.f, 0.f};
        #pragma unroll 4
        for (int j = wave; j < na; j += 8) {
            const float w0 = sc0[j];          // wave-uniform LDS broadcast
            const float w1 = sc1[j];
            const int   rj = actl[j];
            const float4 v4 = *(const float4*)(vb + (size_t)rj * NH);
            o0.x = fmaf(w0, v4.x, o0.x); o0.y = fmaf(w0, v4.y, o0.y);
            o0.z = fmaf(w0, v4.z, o0.z); o0.w = fmaf(w0, v4.w, o0.w);
            o1.x = fmaf(w1, v4.x, o1.x); o1.y = fmaf(w1, v4.y, o1.y);
            o1.z = fmaf(w1, v4.z, o1.z); o1.w = fmaf(w1, v4.w, o1.w);
        }
        __syncthreads();                     // combine reads done; reuse buf4
        buf4[t]       = o0;                   // row 0 partials
        buf4[512 + t] = o1;                   // row 1 partials
        __syncthreads();
        if (t < 128) {
            const int row = t >> 6;           // 0 or 1
            const int l   = t & 63;
            float4 o = buf4[row * 512 + l];
            #pragma unroll
            for (int w = 1; w < 8; ++w) {
                const float4 s = buf4[row * 512 + l + 64 * w];
                o.x += s.x; o.y += s.y; o.z += s.z; o.w += s.w;
            }
            *(float4*)(out_o + (size_t)(b * NLQ + q0 + row) * NH + l * 4) = o;
        }
    }
}

// ---------------------------------------------------------------------------
extern "C" void kernel_launch(void* const* d_in, const int* in_sizes, int n_in,
                              void* d_out, int out_size, void* d_ws, size_t ws_size,
                              hipStream_t stream) {
    const float* query = (const float*)d_in[0];
    const float* key   = (const float*)d_in[1];
    const float* value = (const float*)d_in[2];
    const int*   mask  = (const int*)  d_in[3];
    const float* Wq    = (const float*)d_in[4];
    const float* bq    = (const float*)d_in[5];
    const float* Wk    = (const float*)d_in[6];
    const float* bk    = (const float*)d_in[7];
    const float* v     = (const float*)d_in[8];
    // d_in[9] (bv) drops out of softmax -> unused

    float* out_o = (float*)d_out;                     // [4,256,256]
    float* out_w = out_o + NB * NLQ * NH;             // [4,256,512]

    float* qp    = (float*)d_ws;                      // [4,256,256] Eq
    float* kp_ct = qp + NB * NLQ * NH;                // [4,256,512] Ek compact-T
    int*   act   = (int*)(kp_ct + NB * NH * NLK);     // [4,512]
    int*   nact  = act + NB * NLK;                    // [4]

    const size_t base = (size_t)(NB * NLQ * NH) + (size_t)(NB * NH * NLK)
                      + NB * NLK + NB;                // floats+ints consumed
    float* wtq;
    if (ws_size >= (base + 2 * NH * NH) * sizeof(float)) {
        wtq = (float*)d_ws + base;                    // workspace tail
    } else {
        // park W^T in the out_w tail; attn (after prep) overwrites out_w
        wtq = out_w + (size_t)NB * NLQ * NLK - 2 * NH * NH;
    }
    float* wtk = wtq + NH * NH;

    setup_kernel<<<36, 256, 0, stream>>>(Wq, Wk, mask, wtq, wtk, act, nact);
    prep_kernel<<<NB * NLQ / 4 + NB * NLK / 4, 256, 0, stream>>>(
        query, key, wtq, bq, wtk, bk, act, nact, qp, kp_ct);
    attn_kernel<<<NB * NLQ / 2, 512, 0, stream>>>(
        qp, kp_ct, value, mask, act, nact, v, out_o, out_w);
}